// Round 2
// baseline (119.953 us; speedup 1.0000x reference)
//
#include <hip/hip_runtime.h>
#include <cstdint>
#include <cstddef>

typedef __bf16 bf16;
typedef __bf16 bf16x8 __attribute__((ext_vector_type(8)));
typedef __bf16 bf16x4 __attribute__((ext_vector_type(4)));
typedef float  f32x4  __attribute__((ext_vector_type(4)));

#define MFMA16(a, b, c) __builtin_amdgcn_mfma_f32_16x16x32_bf16(a, b, c, 0, 0, 0)

// ---------------------------------------------------------------------------
// prep: f32 -> bf16 casts (x, W_in, W_out) + q_cls passthrough copy
// xb and wqb are scratch placed INSIDE the attn region of d_out (dead after
// GEMM1, which completes before spatial_attn rewrites attn). wob lives in ws
// (read by GEMM2 after spatial).
// ---------------------------------------------------------------------------
__device__ __forceinline__ void cvt4(const float* __restrict__ s, bf16* __restrict__ d) {
  f32x4 v = *(const f32x4*)s;
  bf16x4 o;
  o[0] = (bf16)v[0]; o[1] = (bf16)v[1]; o[2] = (bf16)v[2]; o[3] = (bf16)v[3];
  *(bf16x4*)d = o;
}

__global__ __launch_bounds__(256) void prep_kernel(
    const float* __restrict__ q, const float* __restrict__ win,
    const float* __restrict__ wout, float* __restrict__ out0,
    bf16* __restrict__ xb, bf16* __restrict__ wqb, bf16* __restrict__ wob) {
  long u = (long)blockIdx.x * 256 + threadIdx.x;
  const long NX4 = 1605632, NWQ4 = 196608, NWO4 = 65536, NQC4 = 1024;
  if (u < NX4) { cvt4(q + 4096 + u * 4, xb + u * 4); return; }
  u -= NX4;
  if (u < NWQ4) { cvt4(win + u * 4, wqb + u * 4); return; }
  u -= NWQ4;
  if (u < NWO4) { cvt4(wout + u * 4, wob + u * 4); return; }
  u -= NWO4;
  if (u < NQC4) { *(f32x4*)(out0 + u * 4) = *(const f32x4*)(q + u * 4); }
}

// ---------------------------------------------------------------------------
// GEMM: C[m][n] = sum_k A[m][k] * B[n][k] + bias[n]
// A: M x K bf16 row-major, B: N x K bf16 row-major (i.e. weight as stored).
// 128x128 tile, BK=32, 4 waves, each wave 64x64 (4x4 frags of 16x16x32).
// ---------------------------------------------------------------------------
template <bool OUTF32>
__global__ __launch_bounds__(256) void gemm_bt(
    const bf16* __restrict__ A, const bf16* __restrict__ Bm,
    const float* __restrict__ bias, bf16* __restrict__ Cb,
    float* __restrict__ Cf, int N, int K, long coff) {
  __shared__ bf16 As[128 * 32];
  __shared__ bf16 Bs[128 * 32];
  const int tid = threadIdx.x;
  const int wid = tid >> 6, lane = tid & 63;
  const int lr = lane & 15, lg = lane >> 4;
  const int m0 = blockIdx.x * 128, n0 = blockIdx.y * 128;
  const int wr = wid >> 1, wc = wid & 1;
  const int sr = tid >> 2;          // 0..63
  const int sc = (tid & 3) * 8;     // 0,8,16,24

  f32x4 acc[4][4] = {};

  for (int kt = 0; kt < K; kt += 32) {
    __syncthreads();
    bf16x8 a0 = *(const bf16x8*)(A + (size_t)(m0 + sr) * K + kt + sc);
    bf16x8 a1 = *(const bf16x8*)(A + (size_t)(m0 + 64 + sr) * K + kt + sc);
    bf16x8 b0 = *(const bf16x8*)(Bm + (size_t)(n0 + sr) * K + kt + sc);
    bf16x8 b1 = *(const bf16x8*)(Bm + (size_t)(n0 + 64 + sr) * K + kt + sc);
    *(bf16x8*)(As + sr * 32 + sc) = a0;
    *(bf16x8*)(As + (64 + sr) * 32 + sc) = a1;
    *(bf16x8*)(Bs + sr * 32 + sc) = b0;
    *(bf16x8*)(Bs + (64 + sr) * 32 + sc) = b1;
    __syncthreads();

    bf16x8 af[4], bfr[4];
#pragma unroll
    for (int m = 0; m < 4; ++m)
      af[m] = *(const bf16x8*)(As + (wr * 64 + m * 16 + lr) * 32 + lg * 8);
#pragma unroll
    for (int n = 0; n < 4; ++n)
      bfr[n] = *(const bf16x8*)(Bs + (wc * 64 + n * 16 + lr) * 32 + lg * 8);
#pragma unroll
    for (int m = 0; m < 4; ++m)
#pragma unroll
      for (int n = 0; n < 4; ++n)
        acc[m][n] = MFMA16(af[m], bfr[n], acc[m][n]);
  }

#pragma unroll
  for (int m = 0; m < 4; ++m) {
    int row = m0 + wr * 64 + m * 16 + lg * 4;
#pragma unroll
    for (int n = 0; n < 4; ++n) {
      int col = n0 + wc * 64 + n * 16 + lr;
      float bv = bias[col];
#pragma unroll
      for (int i = 0; i < 4; ++i) {
        float v = acc[m][n][i] + bv;
        if (OUTF32) Cf[coff + (size_t)(row + i) * N + col] = v;
        else        Cb[(size_t)(row + i) * N + col] = (bf16)v;
      }
    }
  }
}

// ---------------------------------------------------------------------------
// Spatial attention: one block per (h, bb, ti) batch (512 blocks).
// Q/K/V rows p = 0..195, dh = 64. Padded to 224 (14 frags / 7 K-steps).
// Writes attn (f32, output #1) and out_s (bf16, v_t layout [h][bb][p][ti][d]).
// ---------------------------------------------------------------------------
__global__ __launch_bounds__(256) void spatial_attn(
    const bf16* __restrict__ qkv, float* __restrict__ attn_out,
    bf16* __restrict__ outs) {
  __shared__ bf16 Kl[224][72];        // [k-row][d]   pad 72: stride 144B, 2-way
  __shared__ bf16 Vt[64][232];        // [d][k-row]   pad 232: stride 464B, 2-way
  __shared__ bf16 Pl[4][32][232];     // per-wave P tile

  const int tid = threadIdx.x;
  const int wid = tid >> 6, lane = tid & 63;
  const int lr = lane & 15, lg = lane >> 4;
  const int batch = blockIdx.x;            // (h*8 + bb)*8 + ti
  const int ti = batch & 7;
  const int bb = (batch >> 3) & 7;
  const int h = batch >> 6;

  // ---- stage K (row-major) and V (transposed) into LDS, zero-pad rows >=196
  {
    const int p = (tid >> 3);                // row step 32 per iter
    const int c = (tid & 7) * 8;
    bf16 zz = (bf16)0.f;
    for (int r0 = 0; r0 < 224; r0 += 32) {
      int pp = r0 + p;
      bf16x8 kv = {zz, zz, zz, zz, zz, zz, zz, zz};
      bf16x8 vv = {zz, zz, zz, zz, zz, zz, zz, zz};
      if (pp < 196) {
        size_t ro = ((size_t)(ti * 196 + pp) * 8 + bb) * 1536 + h * 64 + c;
        kv = *(const bf16x8*)(qkv + ro + 512);
        vv = *(const bf16x8*)(qkv + ro + 1024);
      }
      *(bf16x8*)&Kl[pp][c] = kv;
#pragma unroll
      for (int j = 0; j < 8; ++j) Vt[c + j][pp] = vv[j];
    }
  }
  __syncthreads();

  // ---- per-wave Q tiles of 32 rows; 7 tiles cover 196 (+pad rows clamped)
  for (int qt = wid; qt < 7; qt += 4) {
    // Q fragments straight from global (small volume, L2-resident)
    bf16x8 aq[2][2];
#pragma unroll
    for (int m = 0; m < 2; ++m) {
      int row = qt * 32 + m * 16 + lr;
      if (row > 195) row = 195;             // clamp; results discarded on write
      size_t ro = ((size_t)(ti * 196 + row) * 8 + bb) * 1536 + h * 64;
#pragma unroll
      for (int kk = 0; kk < 2; ++kk)
        aq[m][kk] = *(const bf16x8*)(qkv + ro + kk * 32 + lg * 8);
    }

    // S = Q K^T : M=32, N=224, K=64
    f32x4 s[2][14] = {};
#pragma unroll
    for (int nn = 0; nn < 14; ++nn) {
      bf16x8 bk0 = *(const bf16x8*)&Kl[nn * 16 + lr][lg * 8];
      bf16x8 bk1 = *(const bf16x8*)&Kl[nn * 16 + lr][32 + lg * 8];
#pragma unroll
      for (int m = 0; m < 2; ++m) {
        s[m][nn] = MFMA16(aq[m][0], bk0, s[m][nn]);
        s[m][nn] = MFMA16(aq[m][1], bk1, s[m][nn]);
      }
    }

    // scale + mask pad cols
#pragma unroll
    for (int nn = 0; nn < 14; ++nn) {
      int col = nn * 16 + lr;
      bool pad = (col >= 196);
#pragma unroll
      for (int m = 0; m < 2; ++m)
#pragma unroll
        for (int i = 0; i < 4; ++i)
          s[m][nn][i] = pad ? -1e30f : s[m][nn][i] * 0.125f;
    }

    // row softmax (rows live on 16-lane groups: same lg, cols = lr x nn)
    float rinv[2][4];
#pragma unroll
    for (int m = 0; m < 2; ++m)
#pragma unroll
      for (int i = 0; i < 4; ++i) {
        float v = -1e30f;
#pragma unroll
        for (int nn = 0; nn < 14; ++nn) v = fmaxf(v, s[m][nn][i]);
#pragma unroll
        for (int d = 1; d < 16; d <<= 1) v = fmaxf(v, __shfl_xor(v, d));
        float sum = 0.f;
#pragma unroll
        for (int nn = 0; nn < 14; ++nn) {
          float e = __expf(s[m][nn][i] - v);
          s[m][nn][i] = e;
          sum += e;
        }
#pragma unroll
        for (int d = 1; d < 16; d <<= 1) sum += __shfl_xor(sum, d);
        rinv[m][i] = 1.f / sum;
      }

    // write attn (output #1) + P into per-wave LDS for PV
#pragma unroll
    for (int nn = 0; nn < 14; ++nn) {
      int col = nn * 16 + lr;
#pragma unroll
      for (int m = 0; m < 2; ++m)
#pragma unroll
        for (int i = 0; i < 4; ++i) {
          float pv = s[m][nn][i] * rinv[m][i];
          int rl = m * 16 + lg * 4 + i;
          int row = qt * 32 + rl;
          if (row < 196 && col < 196)
            attn_out[(size_t)batch * 38416 + (size_t)row * 196 + col] = pv;
          Pl[wid][rl][col] = (bf16)pv;
        }
    }

    // O = P V : M=32, N=64, K=224   (same-wave LDS RAW, compiler orders)
    f32x4 o[2][4] = {};
#pragma unroll
    for (int kb = 0; kb < 7; ++kb) {
      bf16x8 pa[2];
#pragma unroll
      for (int m = 0; m < 2; ++m)
        pa[m] = *(const bf16x8*)&Pl[wid][m * 16 + lr][kb * 32 + lg * 8];
#pragma unroll
      for (int nd = 0; nd < 4; ++nd) {
        bf16x8 vb = *(const bf16x8*)&Vt[nd * 16 + lr][kb * 32 + lg * 8];
#pragma unroll
        for (int m = 0; m < 2; ++m)
          o[m][nd] = MFMA16(pa[m], vb, o[m][nd]);
      }
    }

    // write out_s in v_t layout [h][bb][p][ti][d]
#pragma unroll
    for (int m = 0; m < 2; ++m)
#pragma unroll
      for (int i = 0; i < 4; ++i) {
        int p = qt * 32 + m * 16 + lg * 4 + i;
        if (p < 196) {
#pragma unroll
          for (int nd = 0; nd < 4; ++nd) {
            int d = nd * 16 + lr;
            outs[(((size_t)((h * 8 + bb) * 196 + p)) * 8 + ti) * 64 + d] =
                (bf16)o[m][nd][i];
          }
        }
      }
  }
}

// ---------------------------------------------------------------------------
// Temporal attention: 1 wave per (h, bb, p) batch; t=8, dh=64.
// ---------------------------------------------------------------------------
__global__ __launch_bounds__(256) void temporal_attn(
    const bf16* __restrict__ qkv, const bf16* __restrict__ outs,
    bf16* __restrict__ outt) {
  __shared__ bf16 Ql[4][8][72];
  __shared__ bf16 Kc[4][8][72];
  __shared__ bf16 Vl[4][8][64];
  __shared__ float Ps[4][8][8];

  const int tid = threadIdx.x, wid = tid >> 6, lane = tid & 63;
  const int batch = blockIdx.x * 4 + wid;  // (h*8+bb)*196 + p
  const int p = batch % 196;
  const int hb = batch / 196;
  const int bb = hb & 7, h = hb >> 3;

  const int ri = lane >> 3;        // t-row 0..7
  const int c8 = lane & 7;         // 8-elem chunk of d
  {
    size_t ro = ((size_t)(ri * 196 + p) * 8 + bb) * 1536 + h * 64 + c8 * 8;
    *(bf16x8*)&Ql[wid][ri][c8 * 8] = *(const bf16x8*)(qkv + ro);
    *(bf16x8*)&Kc[wid][ri][c8 * 8] = *(const bf16x8*)(qkv + ro + 512);
    *(bf16x8*)&Vl[wid][ri][c8 * 8] =
        *(const bf16x8*)(outs + ((size_t)batch * 8 + ri) * 64 + c8 * 8);
  }
  __syncthreads();

  // S[i][j] on lane = i*8 + j
  float s = 0.f;
#pragma unroll
  for (int d = 0; d < 64; d += 8) {
    bf16x8 qv = *(const bf16x8*)&Ql[wid][ri][d];
    bf16x8 kv = *(const bf16x8*)&Kc[wid][c8][d];
#pragma unroll
    for (int e = 0; e < 8; ++e) s += (float)qv[e] * (float)kv[e];
  }
  s *= 0.125f;
  float mxv = s;
#pragma unroll
  for (int d2 = 1; d2 < 8; d2 <<= 1) mxv = fmaxf(mxv, __shfl_xor(mxv, d2));
  float e = __expf(s - mxv);
  float sum = e;
#pragma unroll
  for (int d2 = 1; d2 < 8; d2 <<= 1) sum += __shfl_xor(sum, d2);
  Ps[wid][ri][c8] = e / sum;
  __syncthreads();

  // O[i][d], lane = d
  const int d = lane;
#pragma unroll
  for (int ii = 0; ii < 8; ++ii) {
    float o = 0.f;
#pragma unroll
    for (int j = 0; j < 8; ++j) o += Ps[wid][ii][j] * (float)Vl[wid][j][d];
    outt[((size_t)(ii * 196 + p) * 8 + bb) * 512 + h * 64 + d] = (bf16)o;
  }
}

// ---------------------------------------------------------------------------
extern "C" void kernel_launch(void* const* d_in, const int* in_sizes, int n_in,
                              void* d_out, int out_size, void* d_ws,
                              size_t ws_size, hipStream_t stream) {
  (void)in_sizes; (void)n_in; (void)out_size; (void)ws_size;
  const float* q    = (const float*)d_in[0];
  const float* win  = (const float*)d_in[3];
  const float* bin  = (const float*)d_in[4];
  const float* wout = (const float*)d_in[5];
  const float* bout = (const float*)d_in[6];
  float* out0 = (float*)d_out;
  float* attn = out0 + 6426624L;   // 1569*8*512

  // ws layout (64,749,568 bytes total):
  bf16* qkv  = (bf16*)d_ws;                 // 12544*1536       = 19,267,584
  bf16* outs = qkv + 19267584L;             // 8*8*196*8*64     =  6,422,528
  bf16* outt = outs + 6422528L;             // 12544*512        =  6,422,528
  bf16* wob  = outt + 6422528L;             // 512*512          =    262,144

  // gemm1-only scratch lives in the attn region of d_out (78.7 MB, fully
  // rewritten by spatial_attn after gemm1 is done reading these):
  bf16* xb  = (bf16*)attn;                  // 12544*512
  bf16* wqb = xb + 6422528L;                // 1536*512

  prep_kernel<<<7300, 256, 0, stream>>>(q, win, wout, out0, xb, wqb, wob);
  gemm_bt<false><<<dim3(98, 12), 256, 0, stream>>>(xb, wqb, bin, qkv, nullptr,
                                                   1536, 512, 0);
  spatial_attn<<<512, 256, 0, stream>>>(qkv, attn, outs);
  temporal_attn<<<3136, 256, 0, stream>>>(qkv, outs, outt);
  gemm_bt<true><<<dim3(98, 4), 256, 0, stream>>>(outt, wob, bout, nullptr,
                                                 out0, 512, 512, 4096);
}

// Round 3
// 106.446 us; speedup vs baseline: 1.1269x; 1.1269x over previous
//
#include <hip/hip_runtime.h>
#include <cstdint>
#include <cstddef>

typedef __bf16 bf16;
typedef __bf16 bf16x8 __attribute__((ext_vector_type(8)));
typedef __bf16 bf16x4 __attribute__((ext_vector_type(4)));
typedef float  f32x4  __attribute__((ext_vector_type(4)));

#define MFMA16(a, b, c) __builtin_amdgcn_mfma_f32_16x16x32_bf16(a, b, c, 0, 0, 0)

// async global->LDS, 16B per lane, dest = wave-uniform base + lane*16
__device__ __forceinline__ void gl2lds16(const bf16* g, bf16* l) {
  __builtin_amdgcn_global_load_lds(
      (const __attribute__((address_space(1))) void*)g,
      (__attribute__((address_space(3))) void*)l, 16, 0, 0);
}

// ---------------------------------------------------------------------------
// prep: f32 -> bf16 casts (x, W_in, W_out) + q_cls passthrough copy
// ---------------------------------------------------------------------------
__device__ __forceinline__ void cvt4(const float* __restrict__ s, bf16* __restrict__ d) {
  f32x4 v = *(const f32x4*)s;
  bf16x4 o;
  o[0] = (bf16)v[0]; o[1] = (bf16)v[1]; o[2] = (bf16)v[2]; o[3] = (bf16)v[3];
  *(bf16x4*)d = o;
}

__global__ __launch_bounds__(256) void prep_kernel(
    const float* __restrict__ q, const float* __restrict__ win,
    const float* __restrict__ wout, float* __restrict__ out0,
    bf16* __restrict__ xb, bf16* __restrict__ wqb, bf16* __restrict__ wob) {
  long u = (long)blockIdx.x * 256 + threadIdx.x;
  const long NX4 = 1605632, NWQ4 = 196608, NWO4 = 65536, NQC4 = 1024;
  if (u < NX4) { cvt4(q + 4096 + u * 4, xb + u * 4); return; }
  u -= NX4;
  if (u < NWQ4) { cvt4(win + u * 4, wqb + u * 4); return; }
  u -= NWQ4;
  if (u < NWO4) { cvt4(wout + u * 4, wob + u * 4); return; }
  u -= NWO4;
  if (u < NQC4) { *(f32x4*)(out0 + u * 4) = *(const f32x4*)(q + u * 4); }
}

// ---------------------------------------------------------------------------
// GEMM: C[m][n] = sum_k A[m][k] * B[n][k] + bias[n]
// 128x128 tile, BK=32, 4 waves. global_load_lds staging (m97 pattern).
// Grid: x = n-tiles (fastest), y = m-tiles; bijective XCD swizzle
// (nwg % 8 == 0 for both call sites).
// ---------------------------------------------------------------------------
template <bool OUTF32>
__global__ __launch_bounds__(256) void gemm_bt(
    const bf16* __restrict__ A, const bf16* __restrict__ Bm,
    const float* __restrict__ bias, bf16* __restrict__ Cb,
    float* __restrict__ Cf, int N, int K, long coff) {
  __shared__ bf16 As[128 * 32];
  __shared__ bf16 Bs[128 * 32];
  const int tid = threadIdx.x;
  const int wid = tid >> 6, lane = tid & 63;
  const int lr = lane & 15, lg = lane >> 4;

  // XCD-aware swizzle: contiguous chunk of work per XCD
  const int nwg = gridDim.x * gridDim.y;        // multiple of 8
  const int orig = blockIdx.y * gridDim.x + blockIdx.x;
  const int cpx = nwg >> 3;
  const int swz = (orig & 7) * cpx + (orig >> 3);
  const int m0 = (swz / gridDim.x) * 128;
  const int n0 = (swz % gridDim.x) * 128;

  const int wr = wid >> 1, wc = wid & 1;
  // staging: each wave stages 32 rows of As and Bs (2 instrs each of 16 rows)
  const int srow = lane >> 2;                   // 0..15 within 16-row chunk
  const int scol = (lane & 3) * 8;              // 0,8,16,24

  f32x4 acc[4][4] = {};

  for (int kt = 0; kt < K; kt += 32) {
    __syncthreads();   // previous iteration's reads done before overwrite
#pragma unroll
    for (int j = 0; j < 2; ++j) {
      int r0 = wid * 32 + j * 16;
      gl2lds16(A + (size_t)(m0 + r0 + srow) * K + kt + scol, As + r0 * 32);
      gl2lds16(Bm + (size_t)(n0 + r0 + srow) * K + kt + scol, Bs + r0 * 32);
    }
    __syncthreads();   // compiler emits s_waitcnt vmcnt(0) before s_barrier

    bf16x8 af[4], bfr[4];
#pragma unroll
    for (int m = 0; m < 4; ++m)
      af[m] = *(const bf16x8*)(As + (wr * 64 + m * 16 + lr) * 32 + lg * 8);
#pragma unroll
    for (int n = 0; n < 4; ++n)
      bfr[n] = *(const bf16x8*)(Bs + (wc * 64 + n * 16 + lr) * 32 + lg * 8);
#pragma unroll
    for (int m = 0; m < 4; ++m)
#pragma unroll
      for (int n = 0; n < 4; ++n)
        acc[m][n] = MFMA16(af[m], bfr[n], acc[m][n]);
  }

#pragma unroll
  for (int m = 0; m < 4; ++m) {
    int row = m0 + wr * 64 + m * 16 + lg * 4;
#pragma unroll
    for (int n = 0; n < 4; ++n) {
      int col = n0 + wc * 64 + n * 16 + lr;
      float bv = bias[col];
#pragma unroll
      for (int i = 0; i < 4; ++i) {
        float v = acc[m][n][i] + bv;
        if (OUTF32) Cf[coff + (size_t)(row + i) * N + col] = v;
        else        Cb[(size_t)(row + i) * N + col] = (bf16)v;
      }
    }
  }
}

// ---------------------------------------------------------------------------
// Spatial attention: one block per (h, bb, ti) batch (512 blocks), 8 waves.
// Per-wave Q tiles of 16 rows; 13 tiles cover 196 (pad rows clamped).
// Writes attn (f32, output #1) and out_s (bf16, v_t layout [h][bb][p][ti][d]).
// ---------------------------------------------------------------------------
__global__ __launch_bounds__(512) void spatial_attn(
    const bf16* __restrict__ qkv, float* __restrict__ attn_out,
    bf16* __restrict__ outs) {
  __shared__ bf16 Kl[224][72];        // [k-row][d]   pad 72: 2-way only
  __shared__ bf16 Vt[64][232];        // [d][k-row]
  __shared__ bf16 Pl[8][16][232];     // per-wave P tile

  const int tid = threadIdx.x;
  const int wid = tid >> 6, lane = tid & 63;
  const int lr = lane & 15, lg = lane >> 4;
  const int batch = blockIdx.x;            // (h*8 + bb)*8 + ti
  const int ti = batch & 7;
  const int bb = (batch >> 3) & 7;
  const int h = batch >> 6;

  // ---- stage K (row-major) and V (transposed), zero-pad rows >=196
  {
    const int p = (tid >> 3);                // 0..63
    const int c = (tid & 7) * 8;
    bf16 zz = (bf16)0.f;
    for (int r0 = 0; r0 < 224; r0 += 64) {
      int pp = r0 + p;
      bf16x8 kv = {zz, zz, zz, zz, zz, zz, zz, zz};
      bf16x8 vv = {zz, zz, zz, zz, zz, zz, zz, zz};
      if (pp < 196) {
        size_t ro = ((size_t)(ti * 196 + pp) * 8 + bb) * 1536 + h * 64 + c;
        kv = *(const bf16x8*)(qkv + ro + 512);
        vv = *(const bf16x8*)(qkv + ro + 1024);
      }
      if (pp < 224) {
        *(bf16x8*)&Kl[pp][c] = kv;
#pragma unroll
        for (int j = 0; j < 8; ++j) Vt[c + j][pp] = vv[j];
      }
    }
  }
  __syncthreads();

  // ---- per-wave 16-row Q tiles
  for (int qt = wid; qt < 13; qt += 8) {
    bf16x8 aq[2];
    {
      int row = qt * 16 + lr;
      if (row > 195) row = 195;             // clamp; discarded on write
      size_t ro = ((size_t)(ti * 196 + row) * 8 + bb) * 1536 + h * 64;
#pragma unroll
      for (int kk = 0; kk < 2; ++kk)
        aq[kk] = *(const bf16x8*)(qkv + ro + kk * 32 + lg * 8);
    }

    // S = Q K^T : M=16, N=224, K=64
    f32x4 s[14] = {};
#pragma unroll
    for (int nn = 0; nn < 14; ++nn) {
      bf16x8 bk0 = *(const bf16x8*)&Kl[nn * 16 + lr][lg * 8];
      bf16x8 bk1 = *(const bf16x8*)&Kl[nn * 16 + lr][32 + lg * 8];
      s[nn] = MFMA16(aq[0], bk0, s[nn]);
      s[nn] = MFMA16(aq[1], bk1, s[nn]);
    }

    // scale + mask pad cols
#pragma unroll
    for (int nn = 0; nn < 14; ++nn) {
      bool pad = (nn * 16 + lr >= 196);
#pragma unroll
      for (int i = 0; i < 4; ++i)
        s[nn][i] = pad ? -1e30f : s[nn][i] * 0.125f;
    }

    // row softmax (row = lg*4+i, cols spread over lr x nn; 16-lane reduce)
    float rinv[4];
#pragma unroll
    for (int i = 0; i < 4; ++i) {
      float v = -1e30f;
#pragma unroll
      for (int nn = 0; nn < 14; ++nn) v = fmaxf(v, s[nn][i]);
#pragma unroll
      for (int d = 1; d < 16; d <<= 1) v = fmaxf(v, __shfl_xor(v, d));
      float sum = 0.f;
#pragma unroll
      for (int nn = 0; nn < 14; ++nn) {
        float e = __expf(s[nn][i] - v);
        s[nn][i] = e;
        sum += e;
      }
#pragma unroll
      for (int d = 1; d < 16; d <<= 1) sum += __shfl_xor(sum, d);
      rinv[i] = 1.f / sum;
    }

    // write attn (output #1) + P into per-wave LDS for PV
#pragma unroll
    for (int nn = 0; nn < 14; ++nn) {
      int col = nn * 16 + lr;
#pragma unroll
      for (int i = 0; i < 4; ++i) {
        float pv = s[nn][i] * rinv[i];
        int rl = lg * 4 + i;
        int row = qt * 16 + rl;
        if (row < 196 && col < 196)
          attn_out[(size_t)batch * 38416 + (size_t)row * 196 + col] = pv;
        Pl[wid][rl][col] = (bf16)pv;
      }
    }

    // O = P V : M=16, N=64, K=224  (same-wave LDS RAW, compiler orders)
    f32x4 o[4] = {};
#pragma unroll
    for (int kb = 0; kb < 7; ++kb) {
      bf16x8 pa = *(const bf16x8*)&Pl[wid][lr][kb * 32 + lg * 8];
#pragma unroll
      for (int nd = 0; nd < 4; ++nd) {
        bf16x8 vb = *(const bf16x8*)&Vt[nd * 16 + lr][kb * 32 + lg * 8];
        o[nd] = MFMA16(pa, vb, o[nd]);
      }
    }

    // write out_s in v_t layout [h][bb][p][ti][d]
#pragma unroll
    for (int i = 0; i < 4; ++i) {
      int p = qt * 16 + lg * 4 + i;
      if (p < 196) {
#pragma unroll
        for (int nd = 0; nd < 4; ++nd) {
          int d = nd * 16 + lr;
          outs[(((size_t)((h * 8 + bb) * 196 + p)) * 8 + ti) * 64 + d] =
              (bf16)o[nd][i];
        }
      }
    }
  }
}

// ---------------------------------------------------------------------------
// Temporal attention: 1 wave per (h, bb, p) batch; t=8, dh=64.
// ---------------------------------------------------------------------------
__global__ __launch_bounds__(256) void temporal_attn(
    const bf16* __restrict__ qkv, const bf16* __restrict__ outs,
    bf16* __restrict__ outt) {
  __shared__ bf16 Ql[4][8][72];
  __shared__ bf16 Kc[4][8][72];
  __shared__ bf16 Vl[4][8][64];
  __shared__ float Ps[4][8][8];

  const int tid = threadIdx.x, wid = tid >> 6, lane = tid & 63;
  const int batch = blockIdx.x * 4 + wid;  // (h*8+bb)*196 + p
  const int p = batch % 196;
  const int hb = batch / 196;
  const int bb = hb & 7, h = hb >> 3;

  const int ri = lane >> 3;        // t-row 0..7
  const int c8 = lane & 7;         // 8-elem chunk of d
  {
    size_t ro = ((size_t)(ri * 196 + p) * 8 + bb) * 1536 + h * 64 + c8 * 8;
    *(bf16x8*)&Ql[wid][ri][c8 * 8] = *(const bf16x8*)(qkv + ro);
    *(bf16x8*)&Kc[wid][ri][c8 * 8] = *(const bf16x8*)(qkv + ro + 512);
    *(bf16x8*)&Vl[wid][ri][c8 * 8] =
        *(const bf16x8*)(outs + ((size_t)batch * 8 + ri) * 64 + c8 * 8);
  }
  __syncthreads();

  // S[i][j] on lane = i*8 + j
  float s = 0.f;
#pragma unroll
  for (int d = 0; d < 64; d += 8) {
    bf16x8 qv = *(const bf16x8*)&Ql[wid][ri][d];
    bf16x8 kv = *(const bf16x8*)&Kc[wid][c8][d];
#pragma unroll
    for (int e = 0; e < 8; ++e) s += (float)qv[e] * (float)kv[e];
  }
  s *= 0.125f;
  float mxv = s;
#pragma unroll
  for (int d2 = 1; d2 < 8; d2 <<= 1) mxv = fmaxf(mxv, __shfl_xor(mxv, d2));
  float e = __expf(s - mxv);
  float sum = e;
#pragma unroll
  for (int d2 = 1; d2 < 8; d2 <<= 1) sum += __shfl_xor(sum, d2);
  Ps[wid][ri][c8] = e / sum;
  __syncthreads();

  // O[i][d], lane = d
  const int d = lane;
#pragma unroll
  for (int ii = 0; ii < 8; ++ii) {
    float o = 0.f;
#pragma unroll
    for (int j = 0; j < 8; ++j) o += Ps[wid][ii][j] * (float)Vl[wid][j][d];
    outt[((size_t)(ii * 196 + p) * 8 + bb) * 512 + h * 64 + d] = (bf16)o;
  }
}

// ---------------------------------------------------------------------------
extern "C" void kernel_launch(void* const* d_in, const int* in_sizes, int n_in,
                              void* d_out, int out_size, void* d_ws,
                              size_t ws_size, hipStream_t stream) {
  (void)in_sizes; (void)n_in; (void)out_size; (void)ws_size;
  const float* q    = (const float*)d_in[0];
  const float* win  = (const float*)d_in[3];
  const float* bin  = (const float*)d_in[4];
  const float* wout = (const float*)d_in[5];
  const float* bout = (const float*)d_in[6];
  float* out0 = (float*)d_out;
  float* attn = out0 + 6426624L;   // 1569*8*512

  // ws layout (64,749,568 bytes total):
  bf16* qkv  = (bf16*)d_ws;                 // 12544*1536       = 19,267,584
  bf16* outs = qkv + 19267584L;             // 8*8*196*8*64     =  6,422,528
  bf16* outt = outs + 6422528L;             // 12544*512        =  6,422,528
  bf16* wob  = outt + 6422528L;             // 512*512          =    262,144

  // gemm1-only scratch lives in the attn region of d_out (78.7 MB, fully
  // rewritten by spatial_attn after gemm1 is done reading it):
  bf16* xb  = (bf16*)attn;                  // 12544*512
  bf16* wqb = xb + 6422528L;                // 1536*512

  prep_kernel<<<7300, 256, 0, stream>>>(q, win, wout, out0, xb, wqb, wob);
  gemm_bt<false><<<dim3(12, 98), 256, 0, stream>>>(xb, wqb, bin, qkv, nullptr,
                                                   1536, 512, 0);
  spatial_attn<<<512, 512, 0, stream>>>(qkv, attn, outs);
  temporal_attn<<<3136, 256, 0, stream>>>(qkv, outs, outt);
  gemm_bt<true><<<dim3(4, 98), 256, 0, stream>>>(outt, wob, bout, nullptr,
                                                 out0, 512, 512, 4096);
}